// Round 8
// baseline (501.947 us; speedup 1.0000x reference)
//
#include <hip/hip_runtime.h>

typedef _Float16 f16;
typedef _Float16 f16x8 __attribute__((ext_vector_type(8)));
typedef float f32x16 __attribute__((ext_vector_type(16)));

#define MFMA32(A, B, C) __builtin_amdgcn_mfma_f32_32x32x16_f16((A), (B), (C), 0, 0, 0)

__device__ __forceinline__ float sigm_(float x) {
    return __builtin_amdgcn_rcpf(1.f + __builtin_amdgcn_exp2f(-1.44269504088896f * x));
}
__device__ __forceinline__ float tanh_(float x) {
    float e = __builtin_amdgcn_exp2f(2.88539008177793f * x);   // e^(2x)
    return 1.f - 2.f * __builtin_amdgcn_rcpf(1.f + e);
}

// Af XOR swizzle: kills the 8-way bank conflict of the epilogue h-scatter
// (R4: 5.44M conflict cycles -> R7: 0). Lane-uniform in e -> b128 reads OK.
__device__ __forceinline__ int afi(int kt, int lp) {
    return (kt << 6) + (lp ^ (((lp >> 3) ^ kt) & 7));
}

// One prep kernel for all four weight repacks.
// dst layout: [0, 262144)        = W_hh, kt-major slices
//             [262144 + s*65536) = W1/W2/W3, nt-major
__global__ void frag_conv_all(const float* __restrict__ Whh,
                              const float* __restrict__ W1,
                              const float* __restrict__ W2,
                              const float* __restrict__ W3,
                              f16* __restrict__ dst) {
    int idx = blockIdx.x * blockDim.x + threadIdx.x;   // 896*512 = 458752 exact
    if (idx < 262144) {
        int e  = idx & 7;
        int lp = (idx >> 3) & 63;
        int nt = (idx >> 9) & 31;
        int kt = idx >> 14;
        int j = (nt << 5) + (lp & 31);
        int k = (kt << 4) + ((lp >> 5) << 3) + e;
        dst[idx] = (f16)Whh[j * 256 + k];
    } else {
        int r   = idx - 262144;
        int sel = r >> 16;
        int i   = r & 65535;
        const float* W = (sel == 0) ? W1 : (sel == 1) ? W2 : W3;
        int e  = i & 7;
        int lp = (i >> 3) & 63;
        int kt = (i >> 9) & 15;
        int nt = i >> 13;
        int j = (nt << 5) + (lp & 31);
        int k = (kt << 4) + ((lp >> 5) << 3) + e;
        dst[idx] = (f16)W[j * 256 + k];
    }
}

// R8: B fragments load L2 -> REGISTERS (no LDS round-trip; R7 PMC showed the
// LDS port carrying 1.17 MB/step/CU was the bottleneck, not barriers/conflicts).
// W is t-invariant, so the depth-2 register refill cycle (phase KT refills the
// buffer for KT+2, mod 16) runs seamlessly across step boundaries.
// MFMAs consume first, then refill the same named regs (WAR handled by issue order).
#define PHASE(KT, B0, B1, B2, B3) do {                                       \
        f16x8 Av = *(const f16x8*)(Acur + afi((KT), l) * 8);                 \
        acc0 = MFMA32(Av, B0, acc0);                                         \
        acc1 = MFMA32(Av, B1, acc1);                                         \
        acc2 = MFMA32(Av, B2, acc2);                                         \
        acc3 = MFMA32(Av, B3, acc3);                                         \
        {                                                                    \
            const f16* _wp = wb + ((((KT) + 2) & 15) * 16384);               \
            B0 = *(const f16x8*)(_wp);                                       \
            B1 = *(const f16x8*)(_wp + 4096);                                \
            B2 = *(const f16x8*)(_wp + 8192);                                \
            B3 = *(const f16x8*)(_wp + 12288);                               \
        }                                                                    \
        __builtin_amdgcn_sched_barrier(0);                                   \
    } while (0)

__global__ void
__launch_bounds__(512)
__attribute__((amdgpu_waves_per_eu(2, 2)))   // pin allocator budget to 256 VGPR/wave
lstm_fused(const float* __restrict__ statf,   // [8192][256]
           const float* __restrict__ tfg,     // [8192][24]
           const float* __restrict__ tmg,     // [8192][24]
           const float* __restrict__ h0,      // [8192][256]
           const float* __restrict__ c0,      // [8192][256]
           const float* __restrict__ Wih,     // [1024][2]
           const float* __restrict__ bih,     // [1024]
           const float* __restrict__ bhh,     // [1024]
           const float* __restrict__ b1,
           const float* __restrict__ b2,
           const float* __restrict__ b3,
           const float* __restrict__ Wlr,     // [512]
           const float* __restrict__ blr,     // [1]
           const f16* __restrict__ WBH,       // kt-major W_hh frags (512 KB)
           const f16* __restrict__ WB1,       // nt-major W1 frags
           const f16* __restrict__ WB2,
           const f16* __restrict__ WB3,
           float* __restrict__ out)           // [8193]
{
    // ~104 KB LDS: also guarantees 1 block/CU so the 256-VGPR budget is free.
    __shared__ __align__(16) f16 Afb[2][1024][8];  // 32 KB: h fragments, double-buffered
    __shared__ __align__(16) f16 mlpA[2][8192];    // 32 KB: MLP activation ping-pong
    __shared__ float tf_l[32][24];                 // 3 KB
    __shared__ float tm_l[32][24];                 // 3 KB
    __shared__ float wlr_l[512];                   // 2 KB
    __shared__ f16   xa_l[1024];                   // 2 KB
    __shared__ f16   xb_l[1024];                   // 2 KB
    __shared__ float xc_l[1024];                   // 4 KB
    __shared__ __align__(16) f16 padx[12288];      // 24 KB occupancy pad (see guard)

    const int tid = threadIdx.x;
    const int w   = tid >> 6;       // wave 0..7
    const int l   = tid & 63;       // lane
    const int b0  = blockIdx.x * 32;

    if (statf == (const float*)1) padx[0] = (f16)0.f;   // never true; keeps padx

    // per-lane W base: + w*1024B + l*16B (elements: w*512 + l*8)
    const f16* wb = WBH + (w << 9) + (l << 3);

    // ---- prologue: fill B register pair for slices 0,1 ----
    f16x8 Ba0, Ba1, Ba2, Ba3, Bb0, Bb1, Bb2, Bb3;
    {
        const f16* _wp = wb;
        Ba0 = *(const f16x8*)(_wp);
        Ba1 = *(const f16x8*)(_wp + 4096);
        Ba2 = *(const f16x8*)(_wp + 8192);
        Ba3 = *(const f16x8*)(_wp + 12288);
        _wp = wb + 16384;
        Bb0 = *(const f16x8*)(_wp);
        Bb1 = *(const f16x8*)(_wp + 4096);
        Bb2 = *(const f16x8*)(_wp + 8192);
        Bb3 = *(const f16x8*)(_wp + 12288);
    }

    // ---------------- init fills ----------------
    for (int i = tid; i < 32 * 24; i += 512) {
        int r = i / 24, t = i - r * 24;
        tf_l[r][t] = tfg[(b0 + r) * 24 + t];
        tm_l[r][t] = tmg[(b0 + r) * 24 + t];
    }
    wlr_l[tid] = Wlr[tid];
    for (int i = tid; i < 1024; i += 512) {
        xa_l[i] = (f16)Wih[2 * i];
        xb_l[i] = (f16)Wih[2 * i + 1];
        xc_l[i] = bih[i] + bhh[i];
    }
    // h0 -> Afb[0] (swizzled rows)
    for (int i = tid; i < 1024; i += 512) {
        int fr = i >> 6, lp = i & 63;
        int row  = lp & 31;
        int koff = (fr << 4) + ((lp >> 5) << 3);
        const float4* s4 = (const float4*)&h0[(b0 + row) * 256 + koff];
        float4 a = s4[0], b = s4[1];
        f16x8 v;
        v[0]=(f16)a.x; v[1]=(f16)a.y; v[2]=(f16)a.z; v[3]=(f16)a.w;
        v[4]=(f16)b.x; v[5]=(f16)b.y; v[6]=(f16)b.z; v[7]=(f16)b.w;
        *(f16x8*)(&Afb[0][afi(fr, lp)][0]) = v;
    }

    // per-lane constants
    const int jc = (w << 5) + (l & 31);          // this lane's h/gate column
    float cst[16];
    #pragma unroll
    for (int reg = 0; reg < 16; ++reg) {
        int bl = (reg & 3) + ((reg >> 2) << 3) + ((l >> 5) << 2);
        cst[reg] = c0[(b0 + bl) * 256 + jc];
    }
    const int wkt    = jc >> 4;
    const int wlp_hi = ((l >> 3) & 1) << 5;
    const int we     = l & 7;

    // all init ds_writes visible to all waves before the loop
    asm volatile("s_waitcnt lgkmcnt(0)" ::: "memory");
    __builtin_amdgcn_s_barrier();

    // ---------------- LSTM over 24 steps: ONE barrier per step ----------------
    #pragma unroll 1
    for (int t = 0; t < 24; ++t) {
        f16* Acur = &Afb[t & 1][0][0];
        f16* Anxt = &Afb[(t + 1) & 1][0][0];
        f32x16 acc0, acc1, acc2, acc3;
        {
            const float xcv0 = xc_l[jc],       xcv1 = xc_l[256 + jc];
            const float xcv2 = xc_l[512 + jc], xcv3 = xc_l[768 + jc];
            #pragma unroll
            for (int e = 0; e < 16; ++e) {
                acc0[e] = xcv0; acc1[e] = xcv1; acc2[e] = xcv2; acc3[e] = xcv3;
            }
        }

        PHASE(0,  Ba0, Ba1, Ba2, Ba3);  PHASE(1,  Bb0, Bb1, Bb2, Bb3);
        PHASE(2,  Ba0, Ba1, Ba2, Ba3);  PHASE(3,  Bb0, Bb1, Bb2, Bb3);
        PHASE(4,  Ba0, Ba1, Ba2, Ba3);  PHASE(5,  Bb0, Bb1, Bb2, Bb3);
        PHASE(6,  Ba0, Ba1, Ba2, Ba3);  PHASE(7,  Bb0, Bb1, Bb2, Bb3);
        PHASE(8,  Ba0, Ba1, Ba2, Ba3);  PHASE(9,  Bb0, Bb1, Bb2, Bb3);
        PHASE(10, Ba0, Ba1, Ba2, Ba3);  PHASE(11, Bb0, Bb1, Bb2, Bb3);
        PHASE(12, Ba0, Ba1, Ba2, Ba3);  PHASE(13, Bb0, Bb1, Bb2, Bb3);
        PHASE(14, Ba0, Ba1, Ba2, Ba3);  PHASE(15, Bb0, Bb1, Bb2, Bb3);
        // phase 14 refilled slice 0 (Ba), phase 15 slice 1 (Bb): ready for t+1.

        // epilogue: gates -> (c,h); x-consts re-read from LDS (anti-pressure)
        {
            const float xav0 = (float)xa_l[jc],       xav1 = (float)xa_l[256 + jc];
            const float xav2 = (float)xa_l[512 + jc], xav3 = (float)xa_l[768 + jc];
            const float xbv0 = (float)xb_l[jc],       xbv1 = (float)xb_l[256 + jc];
            const float xbv2 = (float)xb_l[512 + jc], xbv3 = (float)xb_l[768 + jc];
            #pragma unroll
            for (int reg = 0; reg < 16; ++reg) {
                const int   bl  = (reg & 3) + ((reg >> 2) << 3) + ((l >> 5) << 2);
                const float tfv = tf_l[bl][t];
                const float tmv = tm_l[bl][t];
                float gi = acc0[reg] + xav0 * tfv + xbv0 * tmv;
                float gf = acc1[reg] + xav1 * tfv + xbv1 * tmv;
                float gg = acc2[reg] + xav2 * tfv + xbv2 * tmv;
                float go = acc3[reg] + xav3 * tfv + xbv3 * tmv;
                float i_ = sigm_(gi);
                float f_ = sigm_(gf);
                float g_ = tanh_(gg);
                float o_ = sigm_(go);
                float c_ = f_ * cst[reg] + i_ * g_;
                cst[reg] = c_;
                float h_ = o_ * tanh_(c_);
                Anxt[afi(wkt, bl | wlp_hi) * 8 + we] = (f16)h_;
            }
        }
        // h writes visible to all waves; B register refills unaffected
        asm volatile("s_waitcnt lgkmcnt(0)" ::: "memory");
        __builtin_amdgcn_s_barrier();
        __builtin_amdgcn_sched_barrier(0);
    }
    // final h lives in Afb[0]

    // ---------------- static MLP (register path for W) ----------------
    f16* A2 = &mlpA[0][0];     // rows of 8 f16, afi-swizzled
    f16* A3 = &mlpA[1][0];

    for (int i = tid; i < 1024; i += 512) {
        int fr = i >> 6, lp = i & 63;
        int row  = lp & 31;
        int koff = (fr << 4) + ((lp >> 5) << 3);
        const float4* s4 = (const float4*)&statf[(b0 + row) * 256 + koff];
        float4 a = s4[0], b = s4[1];
        f16x8 v;
        v[0]=(f16)a.x; v[1]=(f16)a.y; v[2]=(f16)a.z; v[3]=(f16)a.w;
        v[4]=(f16)b.x; v[5]=(f16)b.y; v[6]=(f16)b.z; v[7]=(f16)b.w;
        *(f16x8*)(A2 + afi(fr, lp) * 8) = v;
    }
    __syncthreads();

    {
        const f16*   WBl[3]  = {WB1, WB2, WB3};
        const float* bls[3]  = {b1, b2, b3};
        f16*         ains[3] = {A2, A3, A2};
        f16*         aous[3] = {A3, A2, A3};
        const int lane8 = l << 3;
        #pragma unroll 1
        for (int layer = 0; layer < 3; ++layer) {
            const f16* WL  = WBl[layer];
            f16* ain  = ains[layer];
            f16* aout = aous[layer];
            float bias = bls[layer][jc];
            f32x16 acc2;
            #pragma unroll
            for (int e = 0; e < 16; ++e) acc2[e] = bias;

            f16x8 Bq[2], Aq2[2];
            Bq[0]  = *(const f16x8*)(WL + ((w * 16 + 0) * 512) + lane8);
            Aq2[0] = *(const f16x8*)(ain + afi(0, l) * 8);
            #pragma unroll
            for (int kt = 0; kt < 16; ++kt) {
                const int cb = kt & 1, nb = cb ^ 1;
                if (kt < 15) {
                    Bq[nb]  = *(const f16x8*)(WL + ((w * 16 + (kt + 1)) * 512) + lane8);
                    Aq2[nb] = *(const f16x8*)(ain + afi(kt + 1, l) * 8);
                }
                acc2 = MFMA32(Aq2[cb], Bq[cb], acc2);
            }
            __syncthreads();   // done reading ain before overwriting aout
            #pragma unroll
            for (int reg = 0; reg < 16; ++reg) {
                float v = acc2[reg];
                v = v > 0.f ? v : 0.f;
                const int bl2 = (reg & 3) + ((reg >> 2) << 3) + ((l >> 5) << 2);
                aout[afi(wkt, bl2 | wlp_hi) * 8 + we] = (f16)v;
            }
            __syncthreads();
        }
    }

    // ---------------- classifier: predicts = [h, s3] . Wlr + blr ----------------
    {
        const int r  = (w << 2) + (l >> 4);     // row 0..31
        const int lg = l & 15;
        const int lp = r | (((lg >> 3) & 1) << 5);
        const int ee = lg & 7;
        float sum = 0.f;
        #pragma unroll
        for (int i = 0; i < 16; ++i) {
            int j = lg + (i << 4);
            float hv = (float)Afb[0][afi(i, lp)][ee];
            float sv = (float)A3[afi(i, lp) * 8 + ee];
            sum += hv * wlr_l[j] + sv * wlr_l[256 + j];
        }
        sum += __shfl_xor(sum, 8);
        sum += __shfl_xor(sum, 4);
        sum += __shfl_xor(sum, 2);
        sum += __shfl_xor(sum, 1);
        if (lg == 0) out[b0 + r] = sum + blr[0];
    }
}

__global__ __launch_bounds__(1024)
void bce_kernel(const float* __restrict__ pred, const float* __restrict__ tgt,
                float* __restrict__ lossp) {
    const int tid = threadIdx.x;
    float acc = 0.f;
    for (int i = tid; i < 8192; i += 1024) {
        float p  = pred[i];
        float t  = tgt[i];
        float ax = fabsf(p);
        acc += fmaxf(p, 0.f) - p * t
             + log1pf(__builtin_amdgcn_exp2f(-1.44269504088896f * ax));
    }
    #pragma unroll
    for (int m = 32; m >= 1; m >>= 1) acc += __shfl_xor(acc, m);
    __shared__ float red[16];
    if ((tid & 63) == 0) red[tid >> 6] = acc;
    __syncthreads();
    if (tid < 16) {
        float v = red[tid];
        #pragma unroll
        for (int m = 8; m >= 1; m >>= 1) v += __shfl_xor(v, m);
        if (tid == 0) lossp[0] = v * (1.f / 8192.f);
    }
}

extern "C" void kernel_launch(void* const* d_in, const int* in_sizes, int n_in,
                              void* d_out, int out_size, void* d_ws, size_t ws_size,
                              hipStream_t stream) {
    const float* statf = (const float*)d_in[0];
    const float* tfg   = (const float*)d_in[1];
    const float* tmg   = (const float*)d_in[2];
    const float* tgt   = (const float*)d_in[3];
    const float* h0    = (const float*)d_in[4];
    const float* c0    = (const float*)d_in[5];
    const float* Wih   = (const float*)d_in[6];
    const float* Whh   = (const float*)d_in[7];
    const float* bih   = (const float*)d_in[8];
    const float* bhh   = (const float*)d_in[9];
    const float* W1    = (const float*)d_in[10];
    const float* b1    = (const float*)d_in[11];
    const float* W2    = (const float*)d_in[12];
    const float* b2    = (const float*)d_in[13];
    const float* W3    = (const float*)d_in[14];
    const float* b3    = (const float*)d_in[15];
    const float* Wlr   = (const float*)d_in[16];
    const float* blr   = (const float*)d_in[17];
    float* out = (float*)d_out;

    f16* WBH = (f16*)d_ws;            // 262144 halfs, kt-major
    f16* WB1 = WBH + 262144;          // 65536 halfs each, nt-major
    f16* WB2 = WB1 + 65536;
    f16* WB3 = WB2 + 65536;

    frag_conv_all<<<896, 512, 0, stream>>>(Whh, W1, W2, W3, WBH);

    lstm_fused<<<256, 512, 0, stream>>>(statf, tfg, tmg, h0, c0, Wih, bih, bhh,
                                        b1, b2, b3, Wlr, blr,
                                        WBH, WB1, WB2, WB3, out);

    bce_kernel<<<1, 1024, 0, stream>>>(out, tgt, out + 8192);
}

// Round 9
// 356.374 us; speedup vs baseline: 1.4085x; 1.4085x over previous
//
#include <hip/hip_runtime.h>

typedef _Float16 f16;
typedef _Float16 f16x8 __attribute__((ext_vector_type(8)));
typedef float f32x16 __attribute__((ext_vector_type(16)));

#define MFMA32(A, B, C) __builtin_amdgcn_mfma_f32_32x32x16_f16((A), (B), (C), 0, 0, 0)

__device__ __forceinline__ float sigm_(float x) {
    return __builtin_amdgcn_rcpf(1.f + __builtin_amdgcn_exp2f(-1.44269504088896f * x));
}
__device__ __forceinline__ float tanh_(float x) {
    float e = __builtin_amdgcn_exp2f(2.88539008177793f * x);   // e^(2x)
    return 1.f - 2.f * __builtin_amdgcn_rcpf(1.f + e);
}

// async global->LDS, 16B per lane (dest = wave-uniform base + lane*16)
__device__ __forceinline__ void stage16(const void* g, void* s) {
    __builtin_amdgcn_global_load_lds(
        (const __attribute__((address_space(1))) unsigned int*)(g),
        (__attribute__((address_space(3))) unsigned int*)(s), 16, 0, 0);
}

// Af XOR swizzle (R4->R5: bank conflicts 5.44M -> 0). Lane-uniform in e.
__device__ __forceinline__ int afi(int kt, int lp) {
    return (kt << 6) + (lp ^ (((lp >> 3) ^ kt) & 7));
}

// One prep kernel for all four weight repacks (layout UNCHANGED from R7):
// W_hh kt-major: dst[((kt*32+nt)*64+lane)*8+e], nt = g*8+w.
//   nt  0..15 (gates i,f) -> DMA/LDS path;  nt 16..31 (gates g,o) -> direct-reg path.
__global__ void frag_conv_all(const float* __restrict__ Whh,
                              const float* __restrict__ W1,
                              const float* __restrict__ W2,
                              const float* __restrict__ W3,
                              f16* __restrict__ dst) {
    int idx = blockIdx.x * blockDim.x + threadIdx.x;   // 896*512 = 458752 exact
    if (idx < 262144) {
        int e  = idx & 7;
        int lp = (idx >> 3) & 63;
        int nt = (idx >> 9) & 31;
        int kt = idx >> 14;
        int j = (nt << 5) + (lp & 31);
        int k = (kt << 4) + ((lp >> 5) << 3) + e;
        dst[idx] = (f16)Whh[j * 256 + k];
    } else {
        int r   = idx - 262144;
        int sel = r >> 16;
        int i   = r & 65535;
        const float* W = (sel == 0) ? W1 : (sel == 1) ? W2 : W3;
        int e  = i & 7;
        int lp = (i >> 3) & 63;
        int kt = (i >> 9) & 15;
        int nt = i >> 13;
        int j = (nt << 5) + (lp & 31);
        int k = (kt << 4) + ((lp >> 5) << 3) + e;
        dst[idx] = (f16)W[j * 256 + k];
    }
}

// R9 phase: gates i,f from LDS (DMA-staged 16KB half-slices, wave-private
// chunks); gates g,o straight L2->VGPR (16 regs total, refilled AFTER the
// MFMAs consume them - WAR by issue order, no copies, no extra liveness).
// Issue order/phase: [2 DMA] wait vmcnt(6) [ds_reads + 4 MFMA] [2 reg refills].
// vmcnt(6) = loads issued after slice KT's reg loads (2 DMA + 2 reg of KT+1,
// 2 DMA of KT+2) -> guarantees KT's DMA AND reg data landed.
#define PHASE(KT, PC, PN, B0, B1) do {                                        \
        const int _s2 = ((KT) + 2 + rot) & 15;                                \
        const char* _g = sbL + _s2 * 32768;                                   \
        stage16(_g,        (PN) + dL0);                                       \
        stage16(_g + 8192, (PN) + dL0 + 4096);                                \
        asm volatile("s_waitcnt vmcnt(6)" ::: "memory");                      \
        __builtin_amdgcn_sched_barrier(0);                                    \
        f16x8 Av = *(const f16x8*)(Acur + afi(((KT) + rot) & 15, l) * 8);     \
        f16x8 L0 = *(const f16x8*)((PC) + dL0);                               \
        f16x8 L1 = *(const f16x8*)((PC) + dL0 + 4096);                        \
        acc0 = MFMA32(Av, L0, acc0);                                          \
        acc1 = MFMA32(Av, L1, acc1);                                          \
        acc2 = MFMA32(Av, B0, acc2);                                          \
        acc3 = MFMA32(Av, B1, acc3);                                          \
        {                                                                     \
            const f16* _r = WBH + _s2 * 16384 + rOff;                         \
            B0 = *(const f16x8*)(_r);                                         \
            B1 = *(const f16x8*)(_r + 4096);                                  \
        }                                                                     \
        __builtin_amdgcn_sched_barrier(0);                                    \
    } while (0)

__global__ __launch_bounds__(512)
void lstm_fused(const float* __restrict__ statf,   // [8192][256]
                const float* __restrict__ tfg,     // [8192][24]
                const float* __restrict__ tmg,     // [8192][24]
                const float* __restrict__ h0,      // [8192][256]
                const float* __restrict__ c0,      // [8192][256]
                const float* __restrict__ Wih,     // [1024][2]
                const float* __restrict__ bih,     // [1024]
                const float* __restrict__ bhh,     // [1024]
                const float* __restrict__ b1,
                const float* __restrict__ b2,
                const float* __restrict__ b3,
                const float* __restrict__ Wlr,     // [512]
                const float* __restrict__ blr,     // [1]
                const f16* __restrict__ WBH,       // kt-major W_hh frags (512 KB)
                const f16* __restrict__ WB1,       // nt-major W1 frags
                const f16* __restrict__ WB2,
                const f16* __restrict__ WB3,
                float* __restrict__ out)           // [8193]
{
    // 128 KB LDS -> 1 block/CU.
    __shared__ __align__(16) f16 wsl[3][8192];     // 48 KB: 3 half-slice buffers (i,f gates)
    __shared__ __align__(16) f16 Afb[2][1024][8];  // 32 KB: h fragments, double-buffered
    __shared__ __align__(16) f16 mlpA[2][8192];    // 32 KB: MLP activation ping-pong
    __shared__ float tf_l[32][24];                 // 3 KB
    __shared__ float tm_l[32][24];                 // 3 KB
    __shared__ float wlr_l[512];                   // 2 KB
    __shared__ f16   xa_l[1024];                   // 2 KB
    __shared__ f16   xb_l[1024];                   // 2 KB
    __shared__ float xc_l[1024];                   // 4 KB

    const int tid = threadIdx.x;
    const int w   = tid >> 6;       // wave 0..7
    const int l   = tid & 63;       // lane
    const int b0  = blockIdx.x * 32;
    const int rot = blockIdx.x & 15;   // per-block phase rotation: spreads L2 sets

    // DMA source base (bytes): wave w's chunk within a slice's first half
    const char* sbL = (const char*)WBH + (w << 10) + (l << 4);
    // DMA dest offset (f16 elems) into a 16KB buffer
    const int dL0 = (w << 9) + (l << 3);
    // direct-reg source offset (f16 elems): nt = 16+w (gate g); +4096 -> nt = 24+w (gate o)
    const int rOff = 8192 + (w << 9) + (l << 3);

    // ---------------- init fills ----------------
    for (int i = tid; i < 32 * 24; i += 512) {
        int r = i / 24, t = i - r * 24;
        tf_l[r][t] = tfg[(b0 + r) * 24 + t];
        tm_l[r][t] = tmg[(b0 + r) * 24 + t];
    }
    wlr_l[tid] = Wlr[tid];
    for (int i = tid; i < 1024; i += 512) {
        xa_l[i] = (f16)Wih[2 * i];
        xb_l[i] = (f16)Wih[2 * i + 1];
        xc_l[i] = bih[i] + bhh[i];
    }
    // h0 -> Afb[0] (swizzled rows)
    for (int i = tid; i < 1024; i += 512) {
        int fr = i >> 6, lp = i & 63;
        int row  = lp & 31;
        int koff = (fr << 4) + ((lp >> 5) << 3);
        const float4* s4 = (const float4*)&h0[(b0 + row) * 256 + koff];
        float4 a = s4[0], b = s4[1];
        f16x8 v;
        v[0]=(f16)a.x; v[1]=(f16)a.y; v[2]=(f16)a.z; v[3]=(f16)a.w;
        v[4]=(f16)b.x; v[5]=(f16)b.y; v[6]=(f16)b.z; v[7]=(f16)b.w;
        *(f16x8*)(&Afb[0][afi(fr, lp)][0]) = v;
    }

    // per-lane constants
    const int jc = (w << 5) + (l & 31);          // this lane's h/gate column
    float cst[16];
    #pragma unroll
    for (int reg = 0; reg < 16; ++reg) {
        int bl = (reg & 3) + ((reg >> 2) << 3) + ((l >> 5) << 2);
        cst[reg] = c0[(b0 + bl) * 256 + jc];
    }
    const int wkt    = jc >> 4;
    const int wlp_hi = ((l >> 3) & 1) << 5;
    const int we     = l & 7;

    // FULL drain: init global loads (c0/h0/...) must not pollute vmcnt counting
    asm volatile("s_waitcnt vmcnt(0) lgkmcnt(0)" ::: "memory");
    __builtin_amdgcn_s_barrier();

    f16* p0 = &wsl[0][0];
    f16* p1 = &wsl[1][0];
    f16* p2 = &wsl[2][0];

    // ---- prologue: order-pinned [DMA(s0), REG(s0), DMA(s1), REG(s1)] ----
    f16x8 Bc0, Bc1, Bd0, Bd1;
    {
        const int s0 = rot, s1 = (rot + 1) & 15;
        stage16(sbL + s0 * 32768,        p0 + dL0);
        stage16(sbL + s0 * 32768 + 8192, p0 + dL0 + 4096);
        __builtin_amdgcn_sched_barrier(0);
        const f16* r0 = WBH + s0 * 16384 + rOff;
        Bc0 = *(const f16x8*)(r0);
        Bc1 = *(const f16x8*)(r0 + 4096);
        __builtin_amdgcn_sched_barrier(0);
        stage16(sbL + s1 * 32768,        p1 + dL0);
        stage16(sbL + s1 * 32768 + 8192, p1 + dL0 + 4096);
        __builtin_amdgcn_sched_barrier(0);
        const f16* r1 = WBH + s1 * 16384 + rOff;
        Bd0 = *(const f16x8*)(r1);
        Bd1 = *(const f16x8*)(r1 + 4096);
        __builtin_amdgcn_sched_barrier(0);
    }

    // ---------------- LSTM over 24 steps: ONE barrier per step ----------------
    #pragma unroll 1
    for (int t = 0; t < 24; ++t) {
        f16* Acur = &Afb[t & 1][0][0];
        f16* Anxt = &Afb[(t + 1) & 1][0][0];
        f32x16 acc0, acc1, acc2, acc3;
        {
            const float xcv0 = xc_l[jc],       xcv1 = xc_l[256 + jc];
            const float xcv2 = xc_l[512 + jc], xcv3 = xc_l[768 + jc];
            #pragma unroll
            for (int e = 0; e < 16; ++e) {
                acc0[e] = xcv0; acc1[e] = xcv1; acc2[e] = xcv2; acc3[e] = xcv3;
            }
        }

        // even phases consume/refill Bc pair, odd phases Bd pair
        PHASE(0,  p0, p2, Bc0, Bc1);  PHASE(1,  p1, p0, Bd0, Bd1);
        PHASE(2,  p2, p1, Bc0, Bc1);  PHASE(3,  p0, p2, Bd0, Bd1);
        PHASE(4,  p1, p0, Bc0, Bc1);  PHASE(5,  p2, p1, Bd0, Bd1);
        PHASE(6,  p0, p2, Bc0, Bc1);  PHASE(7,  p1, p0, Bd0, Bd1);
        PHASE(8,  p2, p1, Bc0, Bc1);  PHASE(9,  p0, p2, Bd0, Bd1);
        PHASE(10, p1, p0, Bc0, Bc1);  PHASE(11, p2, p1, Bd0, Bd1);
        PHASE(12, p0, p2, Bc0, Bc1);  PHASE(13, p1, p0, Bd0, Bd1);
        PHASE(14, p2, p1, Bc0, Bc1);  PHASE(15, p0, p2, Bd0, Bd1);
        // phases 14/15 staged+loaded slices 0'/1' of next step (W t-invariant).

        __builtin_amdgcn_sched_barrier(0);

        // epilogue: gates -> (c,h); x-consts re-read from LDS (anti-pressure)
        {
            const float xav0 = (float)xa_l[jc],       xav1 = (float)xa_l[256 + jc];
            const float xav2 = (float)xa_l[512 + jc], xav3 = (float)xa_l[768 + jc];
            const float xbv0 = (float)xb_l[jc],       xbv1 = (float)xb_l[256 + jc];
            const float xbv2 = (float)xb_l[512 + jc], xbv3 = (float)xb_l[768 + jc];
            #pragma unroll
            for (int reg = 0; reg < 16; ++reg) {
                const int   bl  = (reg & 3) + ((reg >> 2) << 3) + ((l >> 5) << 2);
                const float tfv = tf_l[bl][t];
                const float tmv = tm_l[bl][t];
                float gi = acc0[reg] + xav0 * tfv + xbv0 * tmv;
                float gf = acc1[reg] + xav1 * tfv + xbv1 * tmv;
                float gg = acc2[reg] + xav2 * tfv + xbv2 * tmv;
                float go = acc3[reg] + xav3 * tfv + xbv3 * tmv;
                float i_ = sigm_(gi);
                float f_ = sigm_(gf);
                float g_ = tanh_(gg);
                float o_ = sigm_(go);
                float c_ = f_ * cst[reg] + i_ * g_;
                cst[reg] = c_;
                float h_ = o_ * tanh_(c_);
                Anxt[afi(wkt, bl | wlp_hi) * 8 + we] = (f16)h_;
            }
        }
        // h visible to all waves; the 8 in-flight W loads stay pending across it
        asm volatile("s_waitcnt lgkmcnt(0)" ::: "memory");
        __builtin_amdgcn_s_barrier();
        __builtin_amdgcn_sched_barrier(0);

        // rotate slice buffers (16 % 3 == 1)
        f16* tp = p0; p0 = p1; p1 = p2; p2 = tp;
    }
    // final h lives in Afb[0]

    // drain stray stages/loads before the MLP section
    asm volatile("s_waitcnt vmcnt(0)" ::: "memory");
    __builtin_amdgcn_s_barrier();

    // ---------------- static MLP (register path for W) ----------------
    f16* A2 = &mlpA[0][0];     // rows of 8 f16, afi-swizzled
    f16* A3 = &mlpA[1][0];

    for (int i = tid; i < 1024; i += 512) {
        int fr = i >> 6, lp = i & 63;
        int row  = lp & 31;
        int koff = (fr << 4) + ((lp >> 5) << 3);
        const float4* s4 = (const float4*)&statf[(b0 + row) * 256 + koff];
        float4 a = s4[0], b = s4[1];
        f16x8 v;
        v[0]=(f16)a.x; v[1]=(f16)a.y; v[2]=(f16)a.z; v[3]=(f16)a.w;
        v[4]=(f16)b.x; v[5]=(f16)b.y; v[6]=(f16)b.z; v[7]=(f16)b.w;
        *(f16x8*)(A2 + afi(fr, lp) * 8) = v;
    }
    __syncthreads();

    {
        const f16*   WBl[3]  = {WB1, WB2, WB3};
        const float* bls[3]  = {b1, b2, b3};
        f16*         ains[3] = {A2, A3, A2};
        f16*         aous[3] = {A3, A2, A3};
        const int lane8 = l << 3;
        #pragma unroll 1
        for (int layer = 0; layer < 3; ++layer) {
            const f16* WL  = WBl[layer];
            f16* ain  = ains[layer];
            f16* aout = aous[layer];
            float bias = bls[layer][jc];
            f32x16 acc2;
            #pragma unroll
            for (int e = 0; e < 16; ++e) acc2[e] = bias;

            f16x8 Bq[2], Aq2[2];
            Bq[0]  = *(const f16x8*)(WL + ((w * 16 + 0) * 512) + lane8);
            Aq2[0] = *(const f16x8*)(ain + afi(0, l) * 8);
            #pragma unroll
            for (int kt = 0; kt < 16; ++kt) {
                const int cb = kt & 1, nb = cb ^ 1;
                if (kt < 15) {
                    Bq[nb]  = *(const f16x8*)(WL + ((w * 16 + (kt + 1)) * 512) + lane8);
                    Aq2[nb] = *(const f16x8*)(ain + afi(kt + 1, l) * 8);
                }
                acc2 = MFMA32(Aq2[cb], Bq[cb], acc2);
            }
            __syncthreads();   // done reading ain before overwriting aout
            #pragma unroll
            for (int reg = 0; reg < 16; ++reg) {
                float v = acc2[reg];
                v = v > 0.f ? v : 0.f;
                const int bl2 = (reg & 3) + ((reg >> 2) << 3) + ((l >> 5) << 2);
                aout[afi(wkt, bl2 | wlp_hi) * 8 + we] = (f16)v;
            }
            __syncthreads();
        }
    }

    // ---------------- classifier: predicts = [h, s3] . Wlr + blr ----------------
    {
        const int r  = (w << 2) + (l >> 4);     // row 0..31
        const int lg = l & 15;
        const int lp = r | (((lg >> 3) & 1) << 5);
        const int ee = lg & 7;
        float sum = 0.f;
        #pragma unroll
        for (int i = 0; i < 16; ++i) {
            int j = lg + (i << 4);
            float hv = (float)Afb[0][afi(i, lp)][ee];
            float sv = (float)A3[afi(i, lp) * 8 + ee];
            sum += hv * wlr_l[j] + sv * wlr_l[256 + j];
        }
        sum += __shfl_xor(sum, 8);
        sum += __shfl_xor(sum, 4);
        sum += __shfl_xor(sum, 2);
        sum += __shfl_xor(sum, 1);
        if (lg == 0) out[b0 + r] = sum + blr[0];
    }
}

__global__ __launch_bounds__(1024)
void bce_kernel(const float* __restrict__ pred, const float* __restrict__ tgt,
                float* __restrict__ lossp) {
    const int tid = threadIdx.x;
    float acc = 0.f;
    for (int i = tid; i < 8192; i += 1024) {
        float p  = pred[i];
        float t  = tgt[i];
        float ax = fabsf(p);
        acc += fmaxf(p, 0.f) - p * t
             + log1pf(__builtin_amdgcn_exp2f(-1.44269504088896f * ax));
    }
    #pragma unroll
    for (int m = 32; m >= 1; m >>= 1) acc += __shfl_xor(acc, m);
    __shared__ float red[16];
    if ((tid & 63) == 0) red[tid >> 6] = acc;
    __syncthreads();
    if (tid < 16) {
        float v = red[tid];
        #pragma unroll
        for (int m = 8; m >= 1; m >>= 1) v += __shfl_xor(v, m);
        if (tid == 0) lossp[0] = v * (1.f / 8192.f);
    }
}

extern "C" void kernel_launch(void* const* d_in, const int* in_sizes, int n_in,
                              void* d_out, int out_size, void* d_ws, size_t ws_size,
                              hipStream_t stream) {
    const float* statf = (const float*)d_in[0];
    const float* tfg   = (const float*)d_in[1];
    const float* tmg   = (const float*)d_in[2];
    const float* tgt   = (const float*)d_in[3];
    const float* h0    = (const float*)d_in[4];
    const float* c0    = (const float*)d_in[5];
    const float* Wih   = (const float*)d_in[6];
    const float* Whh   = (const float*)d_in[7];
    const float* bih   = (const float*)d_in[8];
    const float* bhh   = (const float*)d_in[9];
    const float* W1    = (const float*)d_in[10];
    const float* b1    = (const float*)d_in[11];
    const float* W2    = (const float*)d_in[12];
    const float* b2    = (const float*)d_in[13];
    const float* W3    = (const float*)d_in[14];
    const float* b3    = (const float*)d_in[15];
    const float* Wlr   = (const float*)d_in[16];
    const float* blr   = (const float*)d_in[17];
    float* out = (float*)d_out;

    f16* WBH = (f16*)d_ws;            // 262144 halfs, kt-major
    f16* WB1 = WBH + 262144;          // 65536 halfs each, nt-major
    f16* WB2 = WB1 + 65536;
    f16* WB3 = WB2 + 65536;

    frag_conv_all<<<896, 512, 0, stream>>>(Whh, W1, W2, W3, WBH);

    lstm_fused<<<256, 512, 0, stream>>>(statf, tfg, tmg, h0, c0, Wih, bih, bhh,
                                        b1, b2, b3, Wlr, blr,
                                        WBH, WB1, WB2, WB3, out);

    bce_kernel<<<1, 1024, 0, stream>>>(out, tgt, out + 8192);
}